// Round 1
// baseline (174.300 us; speedup 1.0000x reference)
//
#include <hip/hip_runtime.h>

#define EDIM 1280
#define BDIM 64
#define HDIM 20
#define PDIM 448
#define DDIM 64
#define NCOL 3840      // 3*EDIM (q,k,v columns fused)
#define NCHUNK 4
#define ECHUNK 320     // EDIM / NCHUNK
#define CPW 8          // columns per wave
#define CPB 32         // columns per block (4 waves)

// ---------------------------------------------------------------------------
// Kernel 1: fused QKV projection, partial sums over e-chunks.
// lane = row (64 rows = 64 lanes). Weight addresses are wave-uniform -> s_load.
// partial layout: [chunk][col][row]  (col in 0..3839)
// ---------------------------------------------------------------------------
__global__ __launch_bounds__(256) void proj_qkv(
    const float* __restrict__ h,
    const float* __restrict__ Wq, const float* __restrict__ Wk,
    const float* __restrict__ Wv,
    float* __restrict__ partial)
{
    const int wave = threadIdx.x >> 6;
    const int lane = threadIdx.x & 63;
    const int colbase = blockIdx.x * CPB + wave * CPW;
    const int e0 = blockIdx.y * ECHUNK;

    const float* W; int wc;
    if (colbase < EDIM)          { W = Wq; wc = colbase; }
    else if (colbase < 2 * EDIM) { W = Wk; wc = colbase - EDIM; }
    else                         { W = Wv; wc = colbase - 2 * EDIM; }

    float acc[CPW];
#pragma unroll
    for (int c = 0; c < CPW; ++c) acc[c] = 0.f;

    const float4* hp = reinterpret_cast<const float4*>(h + lane * EDIM + e0);
#pragma unroll 4
    for (int eg = 0; eg < ECHUNK / 4; ++eg) {
        float4 hv = hp[eg];
#pragma unroll
        for (int c = 0; c < CPW; ++c) {
            float4 wv = *reinterpret_cast<const float4*>(
                W + (size_t)(wc + c) * EDIM + e0 + eg * 4);
            acc[c] += hv.x * wv.x + hv.y * wv.y + hv.z * wv.z + hv.w * wv.w;
        }
    }
#pragma unroll
    for (int c = 0; c < CPW; ++c)
        partial[((size_t)blockIdx.y * NCOL + colbase + c) * 64 + lane] = acc[c];
}

// ---------------------------------------------------------------------------
// Kernel 2: reduce QKV partials; q*(scale)+bq -> ws, k -> d_out seg1,
// v+bv -> d_out seg2. LDS transpose so stores are 16B-contiguous.
// ---------------------------------------------------------------------------
__global__ __launch_bounds__(256) void reduce_proj(
    const float* __restrict__ partial,
    const float* __restrict__ bq, const float* __restrict__ bv,
    float* __restrict__ qout, float* __restrict__ kout, float* __restrict__ vout)
{
    __shared__ float tile[256];
    const int cg0 = blockIdx.x * 4;                 // 4 columns per block
    const int idx = cg0 * 64 + threadIdx.x;         // [col][row] linear
    float v = partial[idx] + partial[245760 + idx]
            + partial[491520 + idx] + partial[737280 + idx];
    tile[threadIdx.x] = v;
    __syncthreads();
    const int row = threadIdx.x >> 2;
    const int c   = threadIdx.x & 3;
    const int cg  = cg0 + c;
    const float v2 = tile[c * 64 + row];
    if (cg < EDIM)
        qout[row * EDIM + cg] = (v2 + bq[cg]) * 0.125f;   // 1/sqrt(64)
    else if (cg < 2 * EDIM)
        kout[row * EDIM + (cg - EDIM)] = v2;              // no k bias
    else
        vout[row * EDIM + (cg - 2 * EDIM)] = v2 + bv[cg - 2 * EDIM];
}

// ---------------------------------------------------------------------------
// Kernel 3: attention decode. One block per (b,h). 449 keys (448 past + new).
// ---------------------------------------------------------------------------
__global__ __launch_bounds__(256) void attn_decode(
    const float* __restrict__ q,       // [64][1280], already scaled
    const float* __restrict__ Kpast,   // [64*20][448][64]
    const float* __restrict__ Vpast,
    const float* __restrict__ mask,    // [448]
    const float* __restrict__ knew,    // [64][1280] (d_out seg1)
    const float* __restrict__ vnew,    // [64][1280] (d_out seg2)
    float* __restrict__ merged)        // [64][1280]
{
    __shared__ float sp[PDIM + 1];
    __shared__ float red[8];
    __shared__ float4 ctxp[4][16];

    const int bh = blockIdx.x;
    const int b  = bh / HDIM;
    const int hh = bh % HDIM;
    const int t  = threadIdx.x;
    const int w  = t >> 6;
    const int lane = t & 63;

    const float* qp = q + b * EDIM + hh * DDIM;      // wave-uniform -> SGPRs
    const float* Kb = Kpast + (size_t)bh * PDIM * DDIM;
    const float* Vb = Vpast + (size_t)bh * PDIM * DDIM;
    const float* nk = knew + b * EDIM + hh * DDIM;
    const float* nv = vnew + b * EDIM + hh * DDIM;

    // ---- phase 1: scores ----
    float lmax = -3.4e38f;
    for (int j = t; j <= PDIM; j += 256) {
        const float* kr = (j < PDIM) ? (Kb + (size_t)j * DDIM) : nk;
        float s = 0.f;
#pragma unroll
        for (int eg = 0; eg < DDIM / 4; ++eg) {
            float4 kv = *reinterpret_cast<const float4*>(kr + eg * 4);
            s += qp[eg * 4 + 0] * kv.x + qp[eg * 4 + 1] * kv.y
               + qp[eg * 4 + 2] * kv.z + qp[eg * 4 + 3] * kv.w;
        }
        if (j < PDIM) s += mask[j];
        sp[j] = s;
        lmax = fmaxf(lmax, s);
    }
#pragma unroll
    for (int o = 32; o > 0; o >>= 1) lmax = fmaxf(lmax, __shfl_xor(lmax, o, 64));
    if (lane == 0) red[w] = lmax;
    __syncthreads();
    const float mx = fmaxf(fmaxf(red[0], red[1]), fmaxf(red[2], red[3]));

    // ---- phase 2: exp + sum ----
    float lsum = 0.f;
    for (int j = t; j <= PDIM; j += 256) {
        float pj = __expf(sp[j] - mx);
        sp[j] = pj;
        lsum += pj;
    }
#pragma unroll
    for (int o = 32; o > 0; o >>= 1) lsum += __shfl_xor(lsum, o, 64);
    if (lane == 0) red[4 + w] = lsum;
    __syncthreads();
    const float inv = 1.f / (red[4] + red[5] + red[6] + red[7]);

    // ---- phase 3: PV. wave handles keys (w + 4*it)*4 + kk; 16 lanes/key ----
    const int kk = lane >> 4;
    const int dg = lane & 15;
    float4 acc = make_float4(0.f, 0.f, 0.f, 0.f);
    for (int jb = w * 4; jb <= PDIM; jb += 16) {
        int j = jb + kk;
        if (j <= PDIM) {
            float pj = sp[j];
            const float* vr = (j < PDIM) ? (Vb + (size_t)j * DDIM) : nv;
            float4 vv = *reinterpret_cast<const float4*>(vr + dg * 4);
            acc.x += pj * vv.x; acc.y += pj * vv.y;
            acc.z += pj * vv.z; acc.w += pj * vv.w;
        }
    }
    acc.x += __shfl_xor(acc.x, 16, 64); acc.y += __shfl_xor(acc.y, 16, 64);
    acc.z += __shfl_xor(acc.z, 16, 64); acc.w += __shfl_xor(acc.w, 16, 64);
    acc.x += __shfl_xor(acc.x, 32, 64); acc.y += __shfl_xor(acc.y, 32, 64);
    acc.z += __shfl_xor(acc.z, 32, 64); acc.w += __shfl_xor(acc.w, 32, 64);
    if (kk == 0) ctxp[w][dg] = acc;
    __syncthreads();
    if (t < 16) {
        float4 a0 = ctxp[0][t], a1 = ctxp[1][t], a2 = ctxp[2][t], a3 = ctxp[3][t];
        float4 r;
        r.x = (a0.x + a1.x + a2.x + a3.x) * inv;
        r.y = (a0.y + a1.y + a2.y + a3.y) * inv;
        r.z = (a0.z + a1.z + a2.z + a3.z) * inv;
        r.w = (a0.w + a1.w + a2.w + a3.w) * inv;
        *reinterpret_cast<float4*>(merged + b * EDIM + hh * DDIM + t * 4) = r;
    }
}

// ---------------------------------------------------------------------------
// Kernel 4: output projection partials (same structure as proj_qkv, 1 matrix)
// ---------------------------------------------------------------------------
__global__ __launch_bounds__(256) void proj_out(
    const float* __restrict__ x,       // merged [64][1280]
    const float* __restrict__ Wo,
    float* __restrict__ partial)       // [chunk][col][row], col in 0..1279
{
    const int wave = threadIdx.x >> 6;
    const int lane = threadIdx.x & 63;
    const int colbase = blockIdx.x * CPB + wave * CPW;
    const int e0 = blockIdx.y * ECHUNK;

    float acc[CPW];
#pragma unroll
    for (int c = 0; c < CPW; ++c) acc[c] = 0.f;

    const float4* xp = reinterpret_cast<const float4*>(x + lane * EDIM + e0);
#pragma unroll 4
    for (int eg = 0; eg < ECHUNK / 4; ++eg) {
        float4 hv = xp[eg];
#pragma unroll
        for (int c = 0; c < CPW; ++c) {
            float4 wv = *reinterpret_cast<const float4*>(
                Wo + (size_t)(colbase + c) * EDIM + e0 + eg * 4);
            acc[c] += hv.x * wv.x + hv.y * wv.y + hv.z * wv.z + hv.w * wv.w;
        }
    }
#pragma unroll
    for (int c = 0; c < CPW; ++c)
        partial[((size_t)blockIdx.y * EDIM + colbase + c) * 64 + lane] = acc[c];
}

// ---------------------------------------------------------------------------
// Kernel 5: reduce output-projection partials + bias -> d_out[0:81920]
// ---------------------------------------------------------------------------
__global__ __launch_bounds__(256) void reduce_out(
    const float* __restrict__ partial, const float* __restrict__ bo,
    float* __restrict__ out)
{
    __shared__ float tile[256];
    const int cg0 = blockIdx.x * 4;
    const int idx = cg0 * 64 + threadIdx.x;
    float v = partial[idx] + partial[81920 + idx]
            + partial[163840 + idx] + partial[245760 + idx];
    tile[threadIdx.x] = v;
    __syncthreads();
    const int row = threadIdx.x >> 2;
    const int c   = threadIdx.x & 3;
    const int cg  = cg0 + c;
    out[row * EDIM + cg] = tile[c * 64 + row] + bo[cg];
}

// ---------------------------------------------------------------------------
extern "C" void kernel_launch(void* const* d_in, const int* in_sizes, int n_in,
                              void* d_out, int out_size, void* d_ws, size_t ws_size,
                              hipStream_t stream)
{
    const float* h    = (const float*)d_in[0];
    const float* pk   = (const float*)d_in[1];
    const float* pv   = (const float*)d_in[2];
    const float* mask = (const float*)d_in[3];
    const float* Wq   = (const float*)d_in[4];
    const float* bq   = (const float*)d_in[5];
    const float* Wk   = (const float*)d_in[6];
    const float* Wv   = (const float*)d_in[7];
    const float* bv   = (const float*)d_in[8];
    const float* Wo   = (const float*)d_in[9];
    const float* bo   = (const float*)d_in[10];

    float* out  = (float*)d_out;            // [64][1280]
    float* kout = (float*)d_out + 81920;    // new_k [64][20][64]
    float* vout = (float*)d_out + 163840;   // new_v

    float* ws    = (float*)d_ws;
    float* partP = ws;                        // 4*3840*64 = 983040 floats
    float* qbuf  = ws + 983040;               // 81920
    float* mrg   = ws + 983040 + 81920;       // 81920
    float* partO = ws + 983040 + 163840;      // 4*1280*64 = 327680

    proj_qkv<<<dim3(NCOL / CPB, NCHUNK), 256, 0, stream>>>(h, Wq, Wk, Wv, partP);
    reduce_proj<<<dim3(NCOL / 4), 256, 0, stream>>>(partP, bq, bv, qbuf, kout, vout);
    attn_decode<<<dim3(BDIM * HDIM), 256, 0, stream>>>(qbuf, pk, pv, mask, kout, vout, mrg);
    proj_out<<<dim3(EDIM / CPB, NCHUNK), 256, 0, stream>>>(mrg, Wo, partO);
    reduce_out<<<dim3(EDIM / 4), 256, 0, stream>>>(partO, bo, out);
}

// Round 2
// 97.302 us; speedup vs baseline: 1.7913x; 1.7913x over previous
//
#include <hip/hip_runtime.h>

#define EDIM 1280
#define BDIM 64
#define HDIM 20
#define PDIM 448
#define DDIM 64
#define NCOL 3840      // 3*EDIM (q,k,v columns fused)
#define NCHUNK 4
#define ECHUNK 320     // EDIM / NCHUNK
#define CTILE 32       // columns per block

__device__ __forceinline__ float dot4(float4 a, float4 b) {
    return a.x * b.x + a.y * b.y + a.z * b.z + a.w * b.w;
}

// ---------------------------------------------------------------------------
// Kernel 1: fused QKV projection, LDS-staged weights.
// Block = 32 cols x 320 e-chunk. Weights staged coalesced into LDS (40KB),
// compute reads LDS with wave-uniform address (broadcast, conflict-free).
// partial layout: [chunk][col][row]
// ---------------------------------------------------------------------------
__global__ __launch_bounds__(256) void proj_qkv(
    const float* __restrict__ h,
    const float* __restrict__ Wq, const float* __restrict__ Wk,
    const float* __restrict__ Wv,
    float* __restrict__ partial)
{
    __shared__ float Wt[CTILE * ECHUNK];   // 40 KB

    const int wave = threadIdx.x >> 6;
    const int lane = threadIdx.x & 63;
    const int colbase = blockIdx.x * CTILE;
    const int e0 = blockIdx.y * ECHUNK;

    const float* W; int wc;
    if (colbase < EDIM)          { W = Wq; wc = colbase; }
    else if (colbase < 2 * EDIM) { W = Wk; wc = colbase - EDIM; }
    else                         { W = Wv; wc = colbase - 2 * EDIM; }

    // stage 32*320 floats = 2560 float4, 10 per thread, coalesced
#pragma unroll
    for (int i = 0; i < 10; ++i) {
        int i4 = (i * 256 + threadIdx.x) * 4;
        int c  = i4 / ECHUNK;
        int e  = i4 - c * ECHUNK;
        *reinterpret_cast<float4*>(&Wt[i4]) =
            *reinterpret_cast<const float4*>(&W[(size_t)(wc + c) * EDIM + e0 + e]);
    }
    __syncthreads();

    float acc[8];
#pragma unroll
    for (int c = 0; c < 8; ++c) acc[c] = 0.f;

    const float4* hp = reinterpret_cast<const float4*>(h + lane * EDIM + e0);
    const int c0 = wave * 8;
#pragma unroll 4
    for (int eg = 0; eg < ECHUNK / 4; ++eg) {
        float4 hv = hp[eg];
#pragma unroll
        for (int c = 0; c < 8; ++c) {
            float4 wv = *reinterpret_cast<const float4*>(&Wt[(c0 + c) * ECHUNK + eg * 4]);
            acc[c] += dot4(hv, wv);
        }
    }
#pragma unroll
    for (int c = 0; c < 8; ++c)
        partial[((size_t)blockIdx.y * NCOL + colbase + c0 + c) * 64 + lane] = acc[c];
}

// ---------------------------------------------------------------------------
// Kernel 2: reduce QKV partials; q*(scale)+bq -> ws, k -> d_out seg1,
// v+bv -> d_out seg2.
// ---------------------------------------------------------------------------
__global__ __launch_bounds__(256) void reduce_proj(
    const float* __restrict__ partial,
    const float* __restrict__ bq, const float* __restrict__ bv,
    float* __restrict__ qout, float* __restrict__ kout, float* __restrict__ vout)
{
    __shared__ float tile[256];
    const int cg0 = blockIdx.x * 4;
    const int idx = cg0 * 64 + threadIdx.x;
    float v = partial[idx] + partial[245760 + idx]
            + partial[491520 + idx] + partial[737280 + idx];
    tile[threadIdx.x] = v;
    __syncthreads();
    const int row = threadIdx.x >> 2;
    const int c   = threadIdx.x & 3;
    const int cg  = cg0 + c;
    const float v2 = tile[c * 64 + row];
    if (cg < EDIM)
        qout[row * EDIM + cg] = (v2 + bq[cg]) * 0.125f;   // 1/sqrt(64)
    else if (cg < 2 * EDIM)
        kout[row * EDIM + (cg - EDIM)] = v2;
    else
        vout[row * EDIM + (cg - 2 * EDIM)] = v2 + bv[cg - 2 * EDIM];
}

// ---------------------------------------------------------------------------
// Kernel 3: attention decode. One block per (b,h). 449 keys.
// Both K and V phases use 16-lanes-per-key coalesced loads (1KB/wave-instr),
// unrolled x4 for outstanding-request depth.
// ---------------------------------------------------------------------------
__global__ __launch_bounds__(256) void attn_decode(
    const float* __restrict__ q,       // [64][1280], already scaled
    const float* __restrict__ Kpast,   // [64*20][448][64]
    const float* __restrict__ Vpast,
    const float* __restrict__ mask,    // [448]
    const float* __restrict__ knew,    // [64][1280]
    const float* __restrict__ vnew,    // [64][1280]
    float* __restrict__ merged)        // [64][1280]
{
    __shared__ float sp[PDIM + 2];
    __shared__ float red[8];
    __shared__ float4 ctxp[4][16];

    const int bh = blockIdx.x;
    const int b  = bh / HDIM;
    const int hh = bh % HDIM;
    const int t  = threadIdx.x;
    const int w  = t >> 6;
    const int lane = t & 63;
    const int grp = t >> 4;     // 0..15: key group
    const int dg  = t & 15;     // float4 index within a 64-float row

    const float* qp = q + b * EDIM + hh * DDIM;
    const float* Kb = Kpast + (size_t)bh * PDIM * DDIM;
    const float* Vb = Vpast + (size_t)bh * PDIM * DDIM;
    const float* nk = knew + b * EDIM + hh * DDIM;
    const float* nv = vnew + b * EDIM + hh * DDIM;

    const float4 qv = *reinterpret_cast<const float4*>(qp + dg * 4);

    // ---- phase 1: scores, 64 keys per block-iteration ----
    float lmax = -3.4e38f;
    for (int j0 = 0; j0 < PDIM; j0 += 64) {
        const int j = j0 + grp;
        float4 k0 = *reinterpret_cast<const float4*>(Kb + (size_t)j * DDIM + dg * 4);
        float4 k1 = *reinterpret_cast<const float4*>(Kb + (size_t)(j + 16) * DDIM + dg * 4);
        float4 k2 = *reinterpret_cast<const float4*>(Kb + (size_t)(j + 32) * DDIM + dg * 4);
        float4 k3 = *reinterpret_cast<const float4*>(Kb + (size_t)(j + 48) * DDIM + dg * 4);
        float s0 = dot4(qv, k0), s1 = dot4(qv, k1), s2 = dot4(qv, k2), s3 = dot4(qv, k3);
#pragma unroll
        for (int off = 8; off; off >>= 1) {
            s0 += __shfl_xor(s0, off, 16);
            s1 += __shfl_xor(s1, off, 16);
            s2 += __shfl_xor(s2, off, 16);
            s3 += __shfl_xor(s3, off, 16);
        }
        if (dg == 0) {
            s0 += mask[j]; s1 += mask[j + 16]; s2 += mask[j + 32]; s3 += mask[j + 48];
            sp[j] = s0; sp[j + 16] = s1; sp[j + 32] = s2; sp[j + 48] = s3;
            lmax = fmaxf(lmax, fmaxf(fmaxf(s0, s1), fmaxf(s2, s3)));
        }
    }
    // new key (index 448), by group 0
    if (grp == 0) {
        float4 kn = *reinterpret_cast<const float4*>(nk + dg * 4);
        float sn = dot4(qv, kn);
#pragma unroll
        for (int off = 8; off; off >>= 1) sn += __shfl_xor(sn, off, 16);
        if (dg == 0) { sp[PDIM] = sn; lmax = fmaxf(lmax, sn); }
    }
#pragma unroll
    for (int off = 32; off; off >>= 1) lmax = fmaxf(lmax, __shfl_xor(lmax, off, 64));
    if (lane == 0) red[w] = lmax;
    __syncthreads();
    const float mx = fmaxf(fmaxf(red[0], red[1]), fmaxf(red[2], red[3]));

    // ---- phase 2: exp + sum ----
    float lsum = 0.f;
    for (int j = t; j <= PDIM; j += 256) {
        float pj = __expf(sp[j] - mx);
        sp[j] = pj;
        lsum += pj;
    }
#pragma unroll
    for (int off = 32; off; off >>= 1) lsum += __shfl_xor(lsum, off, 64);
    if (lane == 0) red[4 + w] = lsum;
    __syncthreads();
    const float inv = 1.f / (red[4] + red[5] + red[6] + red[7]);

    // ---- phase 3: PV, 64 keys per block-iteration, unroll 4 ----
    const int kk = lane >> 4;
    const int dp = lane & 15;
    float4 acc = make_float4(0.f, 0.f, 0.f, 0.f);
    for (int j0 = 0; j0 < PDIM; j0 += 64) {
        const int jb = j0 + w * 16 + kk;           // keys jb, jb+4, jb+8, jb+12
        float p0 = sp[jb], p1 = sp[jb + 4], p2 = sp[jb + 8], p3 = sp[jb + 12];
        float4 v0 = *reinterpret_cast<const float4*>(Vb + (size_t)jb * DDIM + dp * 4);
        float4 v1 = *reinterpret_cast<const float4*>(Vb + (size_t)(jb + 4) * DDIM + dp * 4);
        float4 v2 = *reinterpret_cast<const float4*>(Vb + (size_t)(jb + 8) * DDIM + dp * 4);
        float4 v3 = *reinterpret_cast<const float4*>(Vb + (size_t)(jb + 12) * DDIM + dp * 4);
        acc.x += p0 * v0.x + p1 * v1.x + p2 * v2.x + p3 * v3.x;
        acc.y += p0 * v0.y + p1 * v1.y + p2 * v2.y + p3 * v3.y;
        acc.z += p0 * v0.z + p1 * v1.z + p2 * v2.z + p3 * v3.z;
        acc.w += p0 * v0.w + p1 * v1.w + p2 * v2.w + p3 * v3.w;
    }
    if (w == 0 && kk == 0) {   // new value (index 448)
        float pn = sp[PDIM];
        float4 vn = *reinterpret_cast<const float4*>(nv + dp * 4);
        acc.x += pn * vn.x; acc.y += pn * vn.y; acc.z += pn * vn.z; acc.w += pn * vn.w;
    }
    acc.x += __shfl_xor(acc.x, 16, 64); acc.y += __shfl_xor(acc.y, 16, 64);
    acc.z += __shfl_xor(acc.z, 16, 64); acc.w += __shfl_xor(acc.w, 16, 64);
    acc.x += __shfl_xor(acc.x, 32, 64); acc.y += __shfl_xor(acc.y, 32, 64);
    acc.z += __shfl_xor(acc.z, 32, 64); acc.w += __shfl_xor(acc.w, 32, 64);
    if (kk == 0) ctxp[w][dp] = acc;
    __syncthreads();
    if (t < 16) {
        float4 a0 = ctxp[0][t], a1 = ctxp[1][t], a2 = ctxp[2][t], a3 = ctxp[3][t];
        float4 r;
        r.x = (a0.x + a1.x + a2.x + a3.x) * inv;
        r.y = (a0.y + a1.y + a2.y + a3.y) * inv;
        r.z = (a0.z + a1.z + a2.z + a3.z) * inv;
        r.w = (a0.w + a1.w + a2.w + a3.w) * inv;
        *reinterpret_cast<float4*>(merged + b * EDIM + hh * DDIM + t * 4) = r;
    }
}

// ---------------------------------------------------------------------------
// Kernel 4: output projection, LDS-staged weights (same structure as proj_qkv)
// ---------------------------------------------------------------------------
__global__ __launch_bounds__(256) void proj_out(
    const float* __restrict__ x,       // merged [64][1280]
    const float* __restrict__ Wo,
    float* __restrict__ partial)       // [chunk][col][row]
{
    __shared__ float Wt[CTILE * ECHUNK];

    const int wave = threadIdx.x >> 6;
    const int lane = threadIdx.x & 63;
    const int colbase = blockIdx.x * CTILE;
    const int e0 = blockIdx.y * ECHUNK;

#pragma unroll
    for (int i = 0; i < 10; ++i) {
        int i4 = (i * 256 + threadIdx.x) * 4;
        int c  = i4 / ECHUNK;
        int e  = i4 - c * ECHUNK;
        *reinterpret_cast<float4*>(&Wt[i4]) =
            *reinterpret_cast<const float4*>(&Wo[(size_t)(colbase + c) * EDIM + e0 + e]);
    }
    __syncthreads();

    float acc[8];
#pragma unroll
    for (int c = 0; c < 8; ++c) acc[c] = 0.f;

    const float4* xp = reinterpret_cast<const float4*>(x + lane * EDIM + e0);
    const int c0 = wave * 8;
#pragma unroll 4
    for (int eg = 0; eg < ECHUNK / 4; ++eg) {
        float4 hv = xp[eg];
#pragma unroll
        for (int c = 0; c < 8; ++c) {
            float4 wv = *reinterpret_cast<const float4*>(&Wt[(c0 + c) * ECHUNK + eg * 4]);
            acc[c] += dot4(hv, wv);
        }
    }
#pragma unroll
    for (int c = 0; c < 8; ++c)
        partial[((size_t)blockIdx.y * EDIM + colbase + c0 + c) * 64 + lane] = acc[c];
}

// ---------------------------------------------------------------------------
// Kernel 5: reduce output-projection partials + bias -> d_out[0:81920]
// ---------------------------------------------------------------------------
__global__ __launch_bounds__(256) void reduce_out(
    const float* __restrict__ partial, const float* __restrict__ bo,
    float* __restrict__ out)
{
    __shared__ float tile[256];
    const int cg0 = blockIdx.x * 4;
    const int idx = cg0 * 64 + threadIdx.x;
    float v = partial[idx] + partial[81920 + idx]
            + partial[163840 + idx] + partial[245760 + idx];
    tile[threadIdx.x] = v;
    __syncthreads();
    const int row = threadIdx.x >> 2;
    const int c   = threadIdx.x & 3;
    const int cg  = cg0 + c;
    out[row * EDIM + cg] = tile[c * 64 + row] + bo[cg];
}

// ---------------------------------------------------------------------------
extern "C" void kernel_launch(void* const* d_in, const int* in_sizes, int n_in,
                              void* d_out, int out_size, void* d_ws, size_t ws_size,
                              hipStream_t stream)
{
    const float* h    = (const float*)d_in[0];
    const float* pk   = (const float*)d_in[1];
    const float* pv   = (const float*)d_in[2];
    const float* mask = (const float*)d_in[3];
    const float* Wq   = (const float*)d_in[4];
    const float* bq   = (const float*)d_in[5];
    const float* Wk   = (const float*)d_in[6];
    const float* Wv   = (const float*)d_in[7];
    const float* bv   = (const float*)d_in[8];
    const float* Wo   = (const float*)d_in[9];
    const float* bo   = (const float*)d_in[10];

    float* out  = (float*)d_out;            // [64][1280]
    float* kout = (float*)d_out + 81920;    // new_k [64][20][64]
    float* vout = (float*)d_out + 163840;   // new_v

    float* ws    = (float*)d_ws;
    float* partP = ws;                        // 4*3840*64 = 983040 floats
    float* qbuf  = ws + 983040;               // 81920
    float* mrg   = ws + 983040 + 81920;       // 81920
    float* partO = ws + 983040 + 163840;      // 4*1280*64 = 327680

    proj_qkv<<<dim3(NCOL / CTILE, NCHUNK), 256, 0, stream>>>(h, Wq, Wk, Wv, partP);
    reduce_proj<<<dim3(NCOL / 4), 256, 0, stream>>>(partP, bq, bv, qbuf, kout, vout);
    attn_decode<<<dim3(BDIM * HDIM), 256, 0, stream>>>(qbuf, pk, pv, mask, kout, vout, mrg);
    proj_out<<<dim3(EDIM / CTILE, NCHUNK), 256, 0, stream>>>(mrg, Wo, partO);
    reduce_out<<<dim3(EDIM / 4), 256, 0, stream>>>(partO, bo, out);
}